// Round 8
// baseline (178.716 us; speedup 1.0000x reference)
//
#include <hip/hip_runtime.h>
#include <math.h>

// CBAM pillar kernel for MI355X (gfx950) — round 8.
//
// R7 evidence: per-trip wall ~2100cy/SIMD vs ~600cy static VALU issue, at
// ~2 effective waves/SIMD -> intra-wave dependency stalls dominate (DPP
// hazards, readlane wait-states, the 2 lgkmcnt(0) drains which also drain
// the uniform s_load prefetches).  R8: TWO pillars per wave per trip —
// every serial chain gets an independent twin to fill stall slots; drains,
// loop control and prefetch are shared.  Adjacent pillars -> contiguous pd
// records (SGPR s_loads) and one 512B contiguous output run per wave.

#define NB   32
#define CIN  5
#define CH   32
#define CO   64

__device__ __forceinline__ float frl(float x, int l) {
  return __builtin_bit_cast(float, __builtin_amdgcn_readlane(
      __builtin_bit_cast(int, x), l));
}
template <int C>
__device__ __forceinline__ float dadd(float s) {  // invalid lanes add 0
  int t = __builtin_amdgcn_update_dpp(0, __builtin_bit_cast(int, s),
                                      C, 0xf, 0xf, true);
  return s + __builtin_bit_cast(float, t);
}
template <int C>
__device__ __forceinline__ float dmax(float m) {  // invalid lanes keep m
  int t = __builtin_amdgcn_update_dpp(__builtin_bit_cast(int, m),
                                      __builtin_bit_cast(int, m),
                                      C, 0xf, 0xf, false);
  return fmaxf(m, __builtin_bit_cast(float, t));
}
// 5-step: lane31 = reduce(lanes 0-31), lane63 = reduce(lanes 32-63)
__device__ __forceinline__ float red32_sum(float s) {
  s = dadd<0x111>(s); s = dadd<0x112>(s); s = dadd<0x114>(s);
  s = dadd<0x118>(s); s = dadd<0x142>(s); return s;
}
__device__ __forceinline__ float red32_max(float m) {
  m = dmax<0x111>(m); m = dmax<0x112>(m); m = dmax<0x114>(m);
  m = dmax<0x118>(m); m = dmax<0x142>(m); return m;
}
__device__ __forceinline__ float red64_sum(float s) {
  return dadd<0x143>(red32_sum(s));   // lane63 = full-wave sum
}
__device__ __forceinline__ float red64_max(float m) {
  return dmax<0x143>(red32_max(m));   // lane63 = full-wave max
}
__device__ __forceinline__ float sgm(float x) {
  return 1.0f / (1.0f + __expf(-x));
}
__device__ __forceinline__ void drain_lds() {
  __builtin_amdgcn_wave_barrier();
  __builtin_amdgcn_s_waitcnt(0xC07F);   // lgkmcnt(0)
  __builtin_amdgcn_wave_barrier();
}

// per-voxel: build packed pillar record pd[p] = {vf0[5], vf1[5], b0, b1}
__global__ __launch_bounds__(256) void pack_kernel(
    const float* __restrict__ vf, const int* __restrict__ vcoord,
    const int* __restrict__ unq_inv, float* __restrict__ pd, int n) {
  int i = blockIdx.x * blockDim.x + threadIdx.x;
  if (i >= n) return;
  int p = unq_inv[i];
  int slot = (i > 0 && unq_inv[i - 1] == p) ? 1 : 0;
  float* dst = pd + 12 * (size_t)p;
#pragma unroll
  for (int k = 0; k < 5; ++k) dst[5 * slot + k] = vf[5 * i + k];
  ((int*)dst)[10 + slot] = vcoord[4 * i + 1];
}

__global__ __launch_bounds__(256) void cbam_kernel(
    const float* __restrict__ pd, const int* __restrict__ unq_cnt,
    const float* __restrict__ W1, const float* __restrict__ b1,
    const float* __restrict__ W2, const float* __restrict__ b2,
    const float* __restrict__ Wc1, const float* __restrict__ bc1,
    const float* __restrict__ Wc2, const float* __restrict__ bc2,
    const float* __restrict__ Wsp, const float* __restrict__ bsp,
    float* __restrict__ out, int U, int trips, int totalWaves) {
  const int tid  = threadIdx.x;
  const int lane = tid & 63;
  const int wv   = tid >> 6;
  const int wave0 = blockIdx.x * 4 + wv;

  const int j32  = lane & 31;        // hidden index / bin id
  const int half = lane >> 5;        // voxel-in-pair; channel-half for chMLP
  const int j16  = lane & 15;        // channel-MLP hidden index
  const int pool = (lane >> 4) & 1;  // 0 = avg pool, 1 = max pool

  // ---- persistent per-lane weight registers (loaded once per wave)
  float w1r[CIN];
#pragma unroll
  for (int i = 0; i < CIN; ++i) w1r[i] = W1[i * CH + j32];
  const float b1r = b1[j32];
  float w2r[CH];
#pragma unroll
  for (int j = 0; j < CH; ++j) w2r[j] = W2[j * CO + lane];
  const float b2r = b2[lane];
  float c0 = b2r;                    // MLP output row for an empty bin
#pragma unroll
  for (int j = 0; j < CH; ++j) c0 += fmaxf(b1[j], 0.0f) * w2r[j];
  float wc1r[CH];
#pragma unroll
  for (int s = 0; s < CH; ++s) wc1r[s] = Wc1[(half * 32 + s) * 16 + j16];
  const float bc1r = bc1[j16];
  float wc2r[16];
#pragma unroll
  for (int j = 0; j < 16; ++j) wc2r[j] = Wc2[j * CO + lane];
  const float bc2r = bc2[lane];
  const float bspr = bsp[0];

  // per-lane clipped conv-window weight sums (bin = j32), computed once
  float wsum_m = 0.0f, wsum_x = 0.0f;
#pragma unroll
  for (int k = 0; k < 7; ++k) {
    const bool vld = (unsigned)(j32 + k - 3) < 32u;
    wsum_m += vld ? Wsp[k]     : 0.0f;
    wsum_x += vld ? Wsp[7 + k] : 0.0f;
  }

  // per-wave LDS slice: [0:128) hr broadcast (2 pillars), [128:416) pooled
  __shared__ __align__(16) float lds[4][448];
  __shared__ float2 wtab[8];         // {wm[k], wx[k]}, entry 7 = {0,0}
  if (tid < 8) {
    float a = 0.0f, b = 0.0f;
    if (tid < 7) { a = Wsp[tid]; b = Wsp[7 + tid]; }
    wtab[tid] = make_float2(a, b);
  }
  __syncthreads();
  float* const hrb = lds[wv];
  float* const plb = lds[wv] + 128;
  float* __restrict__ omask = out + (size_t)U * CO;
  const float4* __restrict__ pdv = (const float4*)pd;

  // ---- prologue: load trip-0 records for pillars 2w, 2w+1 (SGPR s_loads)
  float4 Pa[2], Pb[2], Pc[2];
  int cw[2];
  {
    int i0 = 2 * wave0;     i0 = i0 < U ? i0 : (U - 1);
    int i1 = 2 * wave0 + 1; i1 = i1 < U ? i1 : (U - 1);
    Pa[0] = pdv[3 * i0]; Pb[0] = pdv[3 * i0 + 1]; Pc[0] = pdv[3 * i0 + 2];
    Pa[1] = pdv[3 * i1]; Pb[1] = pdv[3 * i1 + 1]; Pc[1] = pdv[3 * i1 + 2];
    cw[0] = unq_cnt[i0]; cw[1] = unq_cnt[i1];
  }

  for (int t = 0; t < trips; ++t) {
    const int w = wave0 + t * totalWaves;
    if (2 * w >= U) break;           // wave-uniform

    // ---- prefetch next trip's records (uniform -> SGPRs, hidden)
    const int wn = w + totalWaves;
    int j0 = 2 * wn;     j0 = j0 < U ? j0 : (U - 1);
    int j1 = 2 * wn + 1; j1 = j1 < U ? j1 : (U - 1);
    const float4 An0 = pdv[3 * j0], Bn0 = pdv[3 * j0 + 1], Cn0 = pdv[3 * j0 + 2];
    const float4 An1 = pdv[3 * j1], Bn1 = pdv[3 * j1 + 1], Cn1 = pdv[3 * j1 + 2];
    const int cn0 = unq_cnt[j0], cn1 = unq_cnt[j1];

    bool has2[2]; int b0[2], b1i[2];
    float hrq[2];
#pragma unroll
    for (int q = 0; q < 2; ++q) {
      has2[q] = (cw[q] >= 2);
      b0[q]  = __builtin_bit_cast(int, Pc[q].z) & 31;
      b1i[q] = __builtin_bit_cast(int, Pc[q].w) & 31;
      // layer 1 (lanes 0-31: voxel0, 32-63: voxel1)
      float h = b1r;
      h += (half ? Pb[q].y : Pa[q].x) * w1r[0];
      h += (half ? Pb[q].z : Pa[q].y) * w1r[1];
      h += (half ? Pb[q].w : Pa[q].z) * w1r[2];
      h += (half ? Pc[q].x : Pa[q].w) * w1r[3];
      h += (half ? Pc[q].y : Pb[q].x) * w1r[4];
      hrq[q] = fmaxf(h, 0.0f);
    }
    hrb[lane]      = hrq[0];
    hrb[64 + lane] = hrq[1];
    drain_lds();

    // ---- layer 2 via LDS broadcast, both pillars interleaved
    float y0[2], y1[2];
#pragma unroll
    for (int q = 0; q < 2; ++q) {
      const float4* h4 = (const float4*)(hrb + 64 * q);
      float a0 = b2r, a1 = 0.0f, a2 = b2r, a3 = 0.0f;
#pragma unroll
      for (int k = 0; k < 4; ++k) {
        float4 a = h4[k];        // voxel0 hr, hidden 4k..4k+3 (broadcast)
        float4 b = h4[4 + k];    // voxel0 hr, hidden 16+4k..
        float4 c = h4[8 + k];    // voxel1 hr
        float4 d = h4[12 + k];
        a0 += a.x * w2r[4 * k]      + a.y * w2r[4 * k + 1] +
              a.z * w2r[4 * k + 2]  + a.w * w2r[4 * k + 3];
        a1 += b.x * w2r[16 + 4 * k]     + b.y * w2r[16 + 4 * k + 1] +
              b.z * w2r[16 + 4 * k + 2] + b.w * w2r[16 + 4 * k + 3];
        a2 += c.x * w2r[4 * k]      + c.y * w2r[4 * k + 1] +
              c.z * w2r[4 * k + 2]  + c.w * w2r[4 * k + 3];
        a3 += d.x * w2r[16 + 4 * k]     + d.y * w2r[16 + 4 * k + 1] +
              d.z * w2r[16 + 4 * k + 2] + d.w * w2r[16 + 4 * k + 3];
      }
      y0[q] = a0 + a1;
      y1[q] = a2 + a3;
    }

    // ---- pooled stats + LDS write (one drain for both pillars)
#pragma unroll
    for (int q = 0; q < 2; ++q) {
      const float sumy = has2[q] ? (y0[q] + y1[q]) : y0[q];
      const float maxy = has2[q] ? fmaxf(y0[q], y1[q]) : y0[q];
      const float avg  = (c0 * (float)(NB - (has2[q] ? 2 : 1)) + sumy) *
                         (1.0f / (float)NB);
      const float mxq  = fmaxf(maxy, c0);
      float* pq = plb + 144 * q;
      pq[half * 36 + j32]      = avg;
      pq[72 + half * 36 + j32] = mxq;
    }
    drain_lds();

    // ---- channel attention, both pillars interleaved
    float attc[2];
#pragma unroll
    for (int q = 0; q < 2; ++q) {
      const float4* r4 = (const float4*)(plb + 144 * q + pool * 72 + half * 36);
      float ta = 0.0f, tb = 0.0f;
#pragma unroll
      for (int k = 0; k < 4; ++k) {
        float4 qq = r4[k];
        float4 uu = r4[4 + k];
        ta += qq.x * wc1r[4 * k]      + qq.y * wc1r[4 * k + 1] +
              qq.z * wc1r[4 * k + 2]  + qq.w * wc1r[4 * k + 3];
        tb += uu.x * wc1r[16 + 4 * k]     + uu.y * wc1r[16 + 4 * k + 1] +
              uu.z * wc1r[16 + 4 * k + 2] + uu.w * wc1r[16 + 4 * k + 3];
      }
      float ttv = ta + tb;
      ttv += __shfl_xor(ttv, 32);                 // combine channel halves
      const float rr = fmaxf(ttv + bc1r, 0.0f);
      const float gg = rr + __shfl_xor(rr, 16);   // relu(h_avg)+relu(h_max)
      float p0 = 2.0f * bc2r, p1 = 0.0f, p2 = 0.0f, p3 = 0.0f;
#pragma unroll
      for (int j = 0; j < 4; ++j) {
        p0 += frl(gg, j)      * wc2r[j];
        p1 += frl(gg, 4 + j)  * wc2r[4 + j];
        p2 += frl(gg, 8 + j)  * wc2r[8 + j];
        p3 += frl(gg, 12 + j) * wc2r[12 + j];
      }
      attc[q] = sgm((p0 + p1) + (p2 + p3));
    }

    // ---- bin attention + final, both pillars interleaved
    float res[2];
#pragma unroll
    for (int q = 0; q < 2; ++q) {
      const float pc0 = attc[q] * c0;
      const float py0 = attc[q] * y0[q];
      const float py1 = attc[q] * y1[q];
      const float aa = half ? py1 : py0;
      const float zx = __shfl_xor(half ? py0 : py1, 32);
      float vs = red32_sum(aa + zx);
      float vm = red32_max(fmaxf(aa, zx));
      const float sy0 = frl(vs, 31), sy1 = frl(vs, 63);
      const float my0 = frl(vm, 31), my1 = frl(vm, 63);
      const float sc  = frl(red64_sum(pc0), 63);
      const float mc  = frl(red64_max(pc0), 63);

      const float inv64 = 1.0f / 64.0f;
      const float Mn = sc * inv64;
      const float Mx = mc;
      int k0 = b0[q] - j32 + 3;  k0 = ((unsigned)k0 <= 6u) ? k0 : 7;
      int k1 = b1i[q] - j32 + 3; k1 = (has2[q] && (unsigned)k1 <= 6u) ? k1 : 7;
      const float2 w0 = wtab[k0];
      const float2 w1c = wtab[k1];
      const float acc = (bspr + Mn * wsum_m + Mx * wsum_x) +
                        (((sy0 - sc) * inv64) * w0.x + (my0 - mc) * w0.y +
                         ((sy1 - sc) * inv64) * w1c.x + (my1 - mc) * w1c.y);

      const bool occ = (j32 == b0[q]) || (has2[q] && (j32 == b1i[q]));
      const float macc =  frl(red32_max(occ ? -3.0e38f :  acc), 31);
      const float nacc = -frl(red32_max(occ ? -3.0e38f : -acc), 31);
      const float sig0 = sgm(frl(acc, b0[q]));
      const float sig1 = sgm(frl(acc, b1i[q]));
      const float sE = sgm(macc);   // max sigmoid over empty bins
      const float sI = sgm(nacc);   // min sigmoid over empty bins

      float m = y0[q] * sig0;
      if (has2[q]) m = fmaxf(m, y1[q] * sig1);
      const float eterm = (c0 >= 0.0f) ? (c0 * sE) : (c0 * sI);
      m = fmaxf(m, eterm);
      res[q] = attc[q] * m;
    }

    // ---- stores: two adjacent 256B rows (512B contiguous per wave)
    const int p0i = 2 * w, p1i = 2 * w + 1;
    out[(size_t)p0i * CO + lane] = res[0];
    if (p1i < U) out[(size_t)p1i * CO + lane] = res[1];
    if (lane < 2) {
      const int pq = p0i + lane;
      if (pq < U)
        omask[pq] = ((lane ? cw[1] : cw[0]) >= 2) ? 1.0f : 0.0f;
    }

    // ---- rotate pipeline registers
    Pa[0] = An0; Pb[0] = Bn0; Pc[0] = Cn0;
    Pa[1] = An1; Pb[1] = Bn1; Pc[1] = Cn1;
    cw[0] = cn0; cw[1] = cn1;
  }
}

extern "C" void kernel_launch(void* const* d_in, const int* in_sizes, int n_in,
                              void* d_out, int out_size, void* d_ws, size_t ws_size,
                              hipStream_t stream) {
  const float* vf      = (const float*)d_in[0];
  const int*   vcoord  = (const int*)d_in[1];
  // d_in[2] = unq_coords (unused: identity)
  const int*   unq_inv = (const int*)d_in[3];
  const int*   unq_cnt = (const int*)d_in[4];
  const float* W1  = (const float*)d_in[5];
  const float* b1  = (const float*)d_in[6];
  const float* W2  = (const float*)d_in[7];
  const float* b2  = (const float*)d_in[8];
  const float* Wc1 = (const float*)d_in[9];
  const float* bc1 = (const float*)d_in[10];
  const float* Wc2 = (const float*)d_in[11];
  const float* bc2 = (const float*)d_in[12];
  const float* Wsp = (const float*)d_in[13];
  const float* bsp = (const float*)d_in[14];

  const int N = in_sizes[3];   // voxels
  const int U = in_sizes[4];   // pillars

  float* pd = (float*)d_ws;    // 12 floats per pillar (4.8 MB @ U=100k)

  pack_kernel<<<(N + 255) / 256, 256, 0, stream>>>(vf, vcoord, unq_inv, pd, N);

  const int blocks = 2048;               // 8192 waves, 2 pillars/wave/trip
  const int totalWaves = blocks * 4;
  const int pairs = (U + 1) / 2;
  const int trips = (pairs + totalWaves - 1) / totalWaves;
  cbam_kernel<<<blocks, 256, 0, stream>>>(
      pd, unq_cnt, W1, b1, W2, b2, Wc1, bc1, Wc2, bc2,
      Wsp, bsp, (float*)d_out, U, trips, totalWaves);
}